// Round 1
// baseline (3249.532 us; speedup 1.0000x reference)
//
#include <hip/hip_runtime.h>
#include <math.h>

#define THREADS 256

// Dims: B=8, C(seq)=10, F(dim)=48, H=W=64, HEADS=8, hd=6, MLP=192
// Stage2: NI=80 images, CH=96, PW=384, OUTF=48

// ---------------- Kernel A: fused 2-layer transformer over 8 sequences/block ----------------
__global__ __launch_bounds__(THREADS) void ka_transformer(
    const float* __restrict__ x,
    const float* __restrict__ qkv_w, const float* __restrict__ qkv_b,
    const float* __restrict__ proj_w, const float* __restrict__ proj_b,
    const float* __restrict__ ff1_w, const float* __restrict__ ff1_b,
    const float* __restrict__ ff2_w, const float* __restrict__ ff2_b,
    float* __restrict__ t_out)
{
    __shared__ float tbuf[8 * 480];    // [s][c*48+f] == [m*48+f], m = s*10+c
    __shared__ float sbuf[8 * 1440];   // qkv [m*144+o] -> o [m*48+hd] -> h1 chunk [mloc*192+j]
    const int tid = threadIdx.x;
    const int blk = blockIdx.x;
    const int b   = blk >> 9;          // 512 blocks per batch image (4096 hw / 8)
    const int hw0 = (blk & 511) << 3;

    // load t tile: t[m][f] = x[(b*480 + c*48 + f)*4096 + hw0 + s]
    for (int idx = tid; idx < 3840; idx += THREADS) {
        int s = idx & 7, cf = idx >> 3;
        tbuf[s * 480 + cf] = x[((size_t)(b * 480 + cf)) * 4096 + hw0 + s];
    }
    __syncthreads();

    for (int l = 0; l < 2; ++l) {
        const float* qw = qkv_w + l * 6912;
        const float* qb = qkv_b + l * 144;
        // ---- qkv GEMM: 80 tokens x 144, 4-row register blocking ----
        for (int task = tid; task < 2880; task += THREADS) {
            int o = task % 144, mg = task / 144;         // mg in [0,20)
            const float* trow = tbuf + mg * 192;
            float a0 = 0.f, a1 = 0.f, a2 = 0.f, a3 = 0.f;
            for (int k = 0; k < 48; ++k) {
                float w = qw[k * 144 + o];
                a0 += trow[k] * w; a1 += trow[48 + k] * w;
                a2 += trow[96 + k] * w; a3 += trow[144 + k] * w;
            }
            float bb = qb[o];
            float* orow = sbuf + mg * 576 + o;
            orow[0] = a0 + bb; orow[144] = a1 + bb; orow[288] = a2 + bb; orow[432] = a3 + bb;
        }
        __syncthreads();

        // ---- banded attention: task = (s,i,h), o[i] = sum_j softmax_j(k_i.q_j) v_j ----
        float ores[3][6];
        #pragma unroll
        for (int it = 0; it < 3; ++it) {
            int task = tid + it * THREADS;
            if (task < 640) {
                int s = task / 80, r = task % 80, i = r / 8, h = r % 8;
                const float* base = sbuf + s * 1440 + h * 6;
                float kv[6];
                #pragma unroll
                for (int d = 0; d < 6; ++d) kv[d] = base[i * 144 + 48 + d];
                int jlo = (i > 0) ? i - 1 : 0;
                int jhi = (i < 9) ? i + 1 : 9;
                float lg[3], mx = -3.4e38f;
                for (int j = jlo; j <= jhi; ++j) {
                    const float* qv = base + j * 144;
                    float sdot = kv[0]*qv[0] + kv[1]*qv[1] + kv[2]*qv[2]
                               + kv[3]*qv[3] + kv[4]*qv[4] + kv[5]*qv[5];
                    sdot *= 0.4082482904638631f;   // 6^-0.5
                    lg[j - jlo] = sdot;
                    mx = fmaxf(mx, sdot);
                }
                int cnt = jhi - jlo + 1;
                float p[3], ps = 0.f;
                for (int jj = 0; jj < cnt; ++jj) { p[jj] = expf(lg[jj] - mx); ps += p[jj]; }
                float inv = 1.0f / ps;
                #pragma unroll
                for (int d = 0; d < 6; ++d) {
                    float ov = 0.f;
                    for (int jj = 0; jj < cnt; ++jj) ov += p[jj] * base[(jlo + jj) * 144 + 96 + d];
                    ores[it][d] = ov * inv;
                }
            }
        }
        __syncthreads();
        #pragma unroll
        for (int it = 0; it < 3; ++it) {
            int task = tid + it * THREADS;
            if (task < 640) {
                int s = task / 80, r = task % 80, i = r / 8, h = r % 8;
                float* dst = sbuf + (s * 10 + i) * 48 + h * 6;
                #pragma unroll
                for (int d = 0; d < 6; ++d) dst[d] = ores[it][d];
            }
        }
        __syncthreads();

        // ---- proj + residual ----
        const float* pw = proj_w + l * 2304;
        const float* pb = proj_b + l * 48;
        for (int task = tid; task < 960; task += THREADS) {
            int f = task % 48, mg = task / 48;
            const float* orow = sbuf + mg * 192;
            float a0 = 0.f, a1 = 0.f, a2 = 0.f, a3 = 0.f;
            for (int k = 0; k < 48; ++k) {
                float w = pw[k * 48 + f];
                a0 += orow[k] * w; a1 += orow[48 + k] * w;
                a2 += orow[96 + k] * w; a3 += orow[144 + k] * w;
            }
            float bb = pb[f];
            float* trow = tbuf + mg * 192 + f;
            trow[0] += a0 + bb; trow[48] += a1 + bb; trow[96] += a2 + bb; trow[144] += a3 + bb;
        }
        __syncthreads();

        // ---- MLP in two 40-token chunks (h1 chunk fits sbuf) ----
        const float* f1w = ff1_w + l * 9216; const float* f1b = ff1_b + l * 192;
        const float* f2w = ff2_w + l * 9216; const float* f2b = ff2_b + l * 48;
        for (int chunk = 0; chunk < 2; ++chunk) {
            const float* tch = tbuf + chunk * 1920;
            for (int task = tid; task < 1920; task += THREADS) {
                int j = task % 192, mg = task / 192;     // mg in [0,10)
                const float* trow = tch + mg * 192;
                float a0 = 0.f, a1 = 0.f, a2 = 0.f, a3 = 0.f;
                for (int k = 0; k < 48; ++k) {
                    float w = f1w[k * 192 + j];
                    a0 += trow[k] * w; a1 += trow[48 + k] * w;
                    a2 += trow[96 + k] * w; a3 += trow[144 + k] * w;
                }
                float bb = f1b[j];
                a0 += bb; a1 += bb; a2 += bb; a3 += bb;
                float* hrow = sbuf + mg * 768 + j;
                hrow[0]   = 0.5f * a0 * (1.f + erff(a0 * 0.70710678118654752f));
                hrow[192] = 0.5f * a1 * (1.f + erff(a1 * 0.70710678118654752f));
                hrow[384] = 0.5f * a2 * (1.f + erff(a2 * 0.70710678118654752f));
                hrow[576] = 0.5f * a3 * (1.f + erff(a3 * 0.70710678118654752f));
            }
            __syncthreads();
            for (int task = tid; task < 480; task += THREADS) {
                int f = task % 48, mg = task / 48;
                const float* hrow = sbuf + mg * 768;
                float a0 = 0.f, a1 = 0.f, a2 = 0.f, a3 = 0.f;
                for (int k = 0; k < 192; ++k) {
                    float w = f2w[k * 48 + f];
                    a0 += hrow[k] * w; a1 += hrow[192 + k] * w;
                    a2 += hrow[384 + k] * w; a3 += hrow[576 + k] * w;
                }
                float bb = f2b[f];
                float* trow = tbuf + chunk * 1920 + mg * 192 + f;
                trow[0] += a0 + bb; trow[48] += a1 + bb; trow[96] += a2 + bb; trow[144] += a3 + bb;
            }
            __syncthreads();
        }
    }

    // store t_final, coalesced (480-float runs per sequence)
    for (int idx = tid; idx < 3840; idx += THREADS) {
        int s = idx / 480, u = idx % 480;
        t_out[(size_t)(b * 4096 + hw0 + s) * 480 + u] = tbuf[idx];
    }
}

// ---------------- Kernel B: depthwise 3x3 conv (SAME) + transpose to pixel-major ----------------
__global__ __launch_bounds__(THREADS) void kb_conv(
    const float* __restrict__ x, const float* __restrict__ t_in,
    const float* __restrict__ dw_w, const float* __restrict__ dw_b,
    float* __restrict__ z0)
{
    __shared__ float ct[100 * 97];     // 10x10 halo tile x 96 ch, stride 97 (bank pad)
    const int tid = threadIdx.x;
    const int blk = blockIdx.x;
    const int n = blk >> 6;            // image (b*10+c)
    const int tile = blk & 63;
    const int th0 = (tile >> 3) << 3;
    const int tw0 = (tile & 7) << 3;
    const int b = n / 10, c = n % 10;

    // x half of cat: channels 0..47, planar layout
    for (int idx = tid; idx < 4800; idx += THREADS) {
        int f = idx / 100, p = idx % 100;
        int py = p / 10, px = p % 10;
        int gh = th0 + py - 1, gw = tw0 + px - 1;
        float v = 0.f;
        if ((unsigned)gh < 64u && (unsigned)gw < 64u)
            v = x[((size_t)n * 48 + f) * 4096 + gh * 64 + gw];
        ct[p * 97 + f] = v;
    }
    // y half of cat: channels 48..95, from t (pixel-major)
    for (int idx = tid; idx < 4800; idx += THREADS) {
        int p = idx / 48, f = idx % 48;
        int py = p / 10, px = p % 10;
        int gh = th0 + py - 1, gw = tw0 + px - 1;
        float v = 0.f;
        if ((unsigned)gh < 64u && (unsigned)gw < 64u)
            v = t_in[(size_t)(b * 4096 + gh * 64 + gw) * 480 + c * 48 + f];
        ct[p * 97 + 48 + f] = v;
    }
    __syncthreads();

    #pragma unroll 4
    for (int it = 0; it < 24; ++it) {
        int oidx = tid + it * THREADS;   // 24*256 == 6144 == 64px * 96ch
        int pxl = oidx / 96, ch = oidx % 96;
        int py = pxl >> 3, pxx = pxl & 7;
        const float* wp = dw_w + ch * 9;
        float acc = dw_b[ch];
        #pragma unroll
        for (int dy = 0; dy < 3; ++dy)
            #pragma unroll
            for (int dx = 0; dx < 3; ++dx)
                acc += ct[((py + dy) * 10 + pxx + dx) * 97 + ch] * wp[dy * 3 + dx];
        z0[((size_t)n * 4096 + (th0 + py) * 64 + (tw0 + pxx)) * 96 + ch] = acc;
    }
}

// ---------------- Kernel C: LN + pw1+gelu+pw2 + shortcut, thread-per-pixel ----------------
__global__ __launch_bounds__(THREADS, 1) void kc_mlp(
    const float* __restrict__ x, const float* __restrict__ t_in,
    const float* __restrict__ z0,
    const float* __restrict__ ln_g, const float* __restrict__ ln_b,
    const float* __restrict__ pw1_w, const float* __restrict__ pw1_b,
    const float* __restrict__ pw2_w, const float* __restrict__ pw2_b,
    const float* __restrict__ sc_w, const float* __restrict__ sc_b,
    float* __restrict__ out)
{
    const int px = blockIdx.x * THREADS + threadIdx.x;   // 327680 pixels
    const int n = px >> 12, hw = px & 4095;

    float z[96];
    {
        const float4* zp = reinterpret_cast<const float4*>(z0 + (size_t)px * 96);
        #pragma unroll
        for (int q = 0; q < 24; ++q) {
            float4 v = zp[q];
            z[4*q] = v.x; z[4*q+1] = v.y; z[4*q+2] = v.z; z[4*q+3] = v.w;
        }
    }
    // LayerNorm over 96 channels
    float mu = 0.f;
    #pragma unroll
    for (int k = 0; k < 96; ++k) mu += z[k];
    mu *= (1.f / 96.f);
    float var = 0.f;
    #pragma unroll
    for (int k = 0; k < 96; ++k) { float d = z[k] - mu; var += d * d; }
    var *= (1.f / 96.f);
    float rs = rsqrtf(var + 1e-6f);
    #pragma unroll
    for (int k = 0; k < 96; ++k) z[k] = (z[k] - mu) * rs * ln_g[k] + ln_b[k];

    // pw1 (96->384) + exact gelu + pw2 (384->48), fused over j
    float acc[48];
    #pragma unroll
    for (int f = 0; f < 48; ++f) acc[f] = pw2_b[f];
    for (int j = 0; j < 384; ++j) {
        float h0 = 0.f, h1 = 0.f, h2 = 0.f, h3 = 0.f;
        #pragma unroll
        for (int k = 0; k < 96; k += 4) {
            h0 += z[k]     * pw1_w[k * 384 + j];
            h1 += z[k + 1] * pw1_w[(k + 1) * 384 + j];
            h2 += z[k + 2] * pw1_w[(k + 2) * 384 + j];
            h3 += z[k + 3] * pw1_w[(k + 3) * 384 + j];
        }
        float hv = (h0 + h1) + (h2 + h3) + pw1_b[j];
        float g = 0.5f * hv * (1.f + erff(hv * 0.70710678118654752f));
        #pragma unroll
        for (int f = 0; f < 48; ++f) acc[f] += g * pw2_w[j * 48 + f];
    }

    // shortcut: sc[f] = sum_ch cat[ch] * sc_w[f*96+ch]
    float cx[96];
    #pragma unroll
    for (int f = 0; f < 48; ++f) cx[f] = x[((size_t)n * 48 + f) * 4096 + hw];
    {
        const float4* cp = reinterpret_cast<const float4*>(
            t_in + (size_t)((n / 10) * 4096 + hw) * 480 + (n % 10) * 48);
        #pragma unroll
        for (int q = 0; q < 12; ++q) {
            float4 v = cp[q];
            cx[48+4*q] = v.x; cx[49+4*q] = v.y; cx[50+4*q] = v.z; cx[51+4*q] = v.w;
        }
    }
    for (int ch = 0; ch < 96; ++ch) {
        float g = cx[ch];
        #pragma unroll
        for (int f = 0; f < 48; ++f) acc[f] += g * sc_w[f * 96 + ch];
    }
    #pragma unroll
    for (int f = 0; f < 48; ++f)
        out[((size_t)n * 48 + f) * 4096 + hw] = acc[f] + sc_b[f];
}

extern "C" void kernel_launch(void* const* d_in, const int* in_sizes, int n_in,
                              void* d_out, int out_size, void* d_ws, size_t ws_size,
                              hipStream_t stream) {
    const float* x      = (const float*)d_in[0];
    const float* qkv_w  = (const float*)d_in[1];
    const float* qkv_b  = (const float*)d_in[2];
    const float* proj_w = (const float*)d_in[3];
    const float* proj_b = (const float*)d_in[4];
    const float* ff1_w  = (const float*)d_in[5];
    const float* ff1_b  = (const float*)d_in[6];
    const float* ff2_w  = (const float*)d_in[7];
    const float* ff2_b  = (const float*)d_in[8];
    const float* dw_w   = (const float*)d_in[9];
    const float* dw_b   = (const float*)d_in[10];
    const float* ln_g   = (const float*)d_in[11];
    const float* ln_b   = (const float*)d_in[12];
    const float* pw1_w  = (const float*)d_in[13];
    const float* pw1_b  = (const float*)d_in[14];
    const float* pw2_w  = (const float*)d_in[15];
    const float* pw2_b  = (const float*)d_in[16];
    const float* sc_w   = (const float*)d_in[17];
    const float* sc_b   = (const float*)d_in[18];
    float* out = (float*)d_out;

    // workspace: t_final (B*H*W,10,48) = 15,728,640 f ; z0 (80*4096,96) = 31,457,280 f
    float* t_out = (float*)d_ws;
    float* z0    = t_out + 15728640ull;

    ka_transformer<<<4096, THREADS, 0, stream>>>(x, qkv_w, qkv_b, proj_w, proj_b,
                                                 ff1_w, ff1_b, ff2_w, ff2_b, t_out);
    kb_conv<<<5120, THREADS, 0, stream>>>(x, t_out, dw_w, dw_b, z0);
    kc_mlp<<<1280, THREADS, 0, stream>>>(x, t_out, z0, ln_g, ln_b,
                                         pw1_w, pw1_b, pw2_w, pw2_b, sc_w, sc_b, out);
}

// Round 2
// 2288.235 us; speedup vs baseline: 1.4201x; 1.4201x over previous
//
#include <hip/hip_runtime.h>
#include <math.h>

#define THREADS 256

// Dims: B=8, C(seq)=10, F(dim)=48, H=W=64, HEADS=8, hd=6, MLP=192
// Stage2: NI=80 images, CH=96, PW=384, OUTF=48

// ---------------- Kernel A: fused 2-layer transformer, 4 sequences/block ----------------
// LDS: tbuf 7.7KB + sbuf 30.7KB = 38.4KB -> 4 blocks/CU (16 waves, ~50% occ)
__global__ __launch_bounds__(THREADS, 4) void ka_transformer(
    const float* __restrict__ x,
    const float* __restrict__ qkv_w, const float* __restrict__ qkv_b,
    const float* __restrict__ proj_w, const float* __restrict__ proj_b,
    const float* __restrict__ ff1_w, const float* __restrict__ ff1_b,
    const float* __restrict__ ff2_w, const float* __restrict__ ff2_b,
    float* __restrict__ t_out)
{
    __shared__ float tbuf[1920];   // [s*480 + c*48 + f] == flat token m=s*10+c at m*48 (m<40)
    __shared__ float sbuf[7680];   // qkv: [m*144+o] ; attn-out: [m*48+hd] ; h1: [m*192+j]
    const int tid = threadIdx.x;
    const int blk = blockIdx.x;          // 8192 blocks
    const int b   = blk >> 10;           // 1024 blocks per batch image (4096 hw / 4)
    const int hw0 = (blk & 1023) << 2;   // 4 pixels per block

    // stage: tbuf[s*480+cf] = x[(b*480+cf)*4096 + hw0 + s], via float4 over s
    for (int cf = tid; cf < 480; cf += THREADS) {
        const float4 v = *(const float4*)(x + ((size_t)(b * 480 + cf)) * 4096 + hw0);
        tbuf[cf] = v.x; tbuf[480 + cf] = v.y; tbuf[960 + cf] = v.z; tbuf[1440 + cf] = v.w;
    }
    __syncthreads();

    for (int l = 0; l < 2; ++l) {
        const float* qw  = qkv_w + l * 6912;
        const float* qb  = qkv_b + l * 144;
        const float* pw  = proj_w + l * 2304;
        const float* pb  = proj_b + l * 48;
        const float* f1w = ff1_w + l * 9216;
        const float* f1b = ff1_b + l * 192;
        const float* f2w = ff2_w + l * 9216;
        const float* f2b = ff2_b + l * 48;

        // ---- qkv: 40x144 = 240 tasks of 4 rows x 6 cols, K=48 ----
        if (tid < 240) {
            const int og = tid % 24, mg = tid / 24;
            const int o0 = og * 6, m0 = mg * 4;
            const float* trow = tbuf + m0 * 48;
            float acc[4][6] = {};
            for (int k = 0; k < 48; k += 4) {
                float4 a0 = *(const float4*)(trow + k);
                float4 a1 = *(const float4*)(trow + 48 + k);
                float4 a2 = *(const float4*)(trow + 96 + k);
                float4 a3 = *(const float4*)(trow + 144 + k);
                #pragma unroll
                for (int kk = 0; kk < 4; ++kk) {
                    const float* wr = qw + (k + kk) * 144 + o0;
                    const float e0 = (&a0.x)[kk], e1 = (&a1.x)[kk], e2 = (&a2.x)[kk], e3 = (&a3.x)[kk];
                    #pragma unroll
                    for (int c = 0; c < 6; ++c) {
                        const float w = wr[c];
                        acc[0][c] += e0 * w; acc[1][c] += e1 * w;
                        acc[2][c] += e2 * w; acc[3][c] += e3 * w;
                    }
                }
            }
            #pragma unroll
            for (int r = 0; r < 4; ++r)
                #pragma unroll
                for (int c = 0; c < 6; ++c)
                    sbuf[(m0 + r) * 144 + o0 + c] = acc[r][c] + qb[o0 + c];
        }
        __syncthreads();

        // ---- banded attention: 4 seq x 10 i x 8 h = 320 tasks ----
        float ores[2][6];
        #pragma unroll
        for (int it = 0; it < 2; ++it) {
            int task = tid + it * THREADS;
            if (task < 320) {
                int s = task / 80, r = task % 80, i = r / 8, h = r % 8;
                const float* base = sbuf + s * 1440 + h * 6;
                float kv[6];
                #pragma unroll
                for (int d = 0; d < 6; ++d) kv[d] = base[i * 144 + 48 + d];
                int jlo = (i > 0) ? i - 1 : 0;
                int jhi = (i < 9) ? i + 1 : 9;
                float lg[3], mx = -3.4e38f;
                for (int j = jlo; j <= jhi; ++j) {
                    const float* qv = base + j * 144;
                    float sdot = kv[0]*qv[0] + kv[1]*qv[1] + kv[2]*qv[2]
                               + kv[3]*qv[3] + kv[4]*qv[4] + kv[5]*qv[5];
                    sdot *= 0.4082482904638631f;   // 6^-0.5
                    lg[j - jlo] = sdot;
                    mx = fmaxf(mx, sdot);
                }
                int cnt = jhi - jlo + 1;
                float p[3], ps = 0.f;
                for (int jj = 0; jj < cnt; ++jj) { p[jj] = expf(lg[jj] - mx); ps += p[jj]; }
                float inv = 1.0f / ps;
                #pragma unroll
                for (int d = 0; d < 6; ++d) {
                    float ov = 0.f;
                    for (int jj = 0; jj < cnt; ++jj) ov += p[jj] * base[(jlo + jj) * 144 + 96 + d];
                    ores[it][d] = ov * inv;
                }
            }
        }
        __syncthreads();
        #pragma unroll
        for (int it = 0; it < 2; ++it) {
            int task = tid + it * THREADS;
            if (task < 320) {
                int s = task / 80, r = task % 80, i = r / 8, h = r % 8;
                float* dst = sbuf + (s * 10 + i) * 48 + h * 6;
                #pragma unroll
                for (int d = 0; d < 6; ++d) dst[d] = ores[it][d];
            }
        }
        __syncthreads();

        // ---- proj + residual: 40x48 = 240 tasks of 4 rows x 2 cols, K=48 ----
        if (tid < 240) {
            const int og = tid % 24, mg = tid / 24;
            const int o0 = og * 2, m0 = mg * 4;
            const float* orow = sbuf + m0 * 48;
            float acc[4][2] = {};
            for (int k = 0; k < 48; k += 4) {
                float4 a0 = *(const float4*)(orow + k);
                float4 a1 = *(const float4*)(orow + 48 + k);
                float4 a2 = *(const float4*)(orow + 96 + k);
                float4 a3 = *(const float4*)(orow + 144 + k);
                #pragma unroll
                for (int kk = 0; kk < 4; ++kk) {
                    const float* wr = pw + (k + kk) * 48 + o0;
                    const float w0 = wr[0], w1 = wr[1];
                    const float e0 = (&a0.x)[kk], e1 = (&a1.x)[kk], e2 = (&a2.x)[kk], e3 = (&a3.x)[kk];
                    acc[0][0] += e0 * w0; acc[0][1] += e0 * w1;
                    acc[1][0] += e1 * w0; acc[1][1] += e1 * w1;
                    acc[2][0] += e2 * w0; acc[2][1] += e2 * w1;
                    acc[3][0] += e3 * w0; acc[3][1] += e3 * w1;
                }
            }
            #pragma unroll
            for (int r = 0; r < 4; ++r)
                #pragma unroll
                for (int c = 0; c < 2; ++c)
                    tbuf[(m0 + r) * 48 + o0 + c] += acc[r][c] + pb[o0 + c];
        }
        __syncthreads();

        // ---- ff1 + gelu: 40x192 = 240 tasks of 4 rows x 8 cols, K=48 ----
        if (tid < 240) {
            const int og = tid % 24, mg = tid / 24;
            const int o0 = og * 8, m0 = mg * 4;
            const float* trow = tbuf + m0 * 48;
            float acc[4][8] = {};
            for (int k = 0; k < 48; k += 4) {
                float4 a0 = *(const float4*)(trow + k);
                float4 a1 = *(const float4*)(trow + 48 + k);
                float4 a2 = *(const float4*)(trow + 96 + k);
                float4 a3 = *(const float4*)(trow + 144 + k);
                #pragma unroll
                for (int kk = 0; kk < 4; ++kk) {
                    const float* wr = f1w + (k + kk) * 192 + o0;
                    const float e0 = (&a0.x)[kk], e1 = (&a1.x)[kk], e2 = (&a2.x)[kk], e3 = (&a3.x)[kk];
                    #pragma unroll
                    for (int c = 0; c < 8; ++c) {
                        const float w = wr[c];
                        acc[0][c] += e0 * w; acc[1][c] += e1 * w;
                        acc[2][c] += e2 * w; acc[3][c] += e3 * w;
                    }
                }
            }
            #pragma unroll
            for (int r = 0; r < 4; ++r)
                #pragma unroll
                for (int c = 0; c < 8; ++c) {
                    float v = acc[r][c] + f1b[o0 + c];
                    v = 0.5f * v * (1.f + erff(v * 0.70710678118654752f));
                    sbuf[(m0 + r) * 192 + o0 + c] = v;
                }
        }
        __syncthreads();

        // ---- ff2 + residual: 40x48 = 240 tasks of 4 rows x 2 cols, K=192 ----
        if (tid < 240) {
            const int og = tid % 24, mg = tid / 24;
            const int o0 = og * 2, m0 = mg * 4;
            const float* hrow = sbuf + m0 * 192;
            float acc[4][2] = {};
            for (int k = 0; k < 192; k += 4) {
                float4 a0 = *(const float4*)(hrow + k);
                float4 a1 = *(const float4*)(hrow + 192 + k);
                float4 a2 = *(const float4*)(hrow + 384 + k);
                float4 a3 = *(const float4*)(hrow + 576 + k);
                #pragma unroll
                for (int kk = 0; kk < 4; ++kk) {
                    const float* wr = f2w + (k + kk) * 48 + o0;
                    const float w0 = wr[0], w1 = wr[1];
                    const float e0 = (&a0.x)[kk], e1 = (&a1.x)[kk], e2 = (&a2.x)[kk], e3 = (&a3.x)[kk];
                    acc[0][0] += e0 * w0; acc[0][1] += e0 * w1;
                    acc[1][0] += e1 * w0; acc[1][1] += e1 * w1;
                    acc[2][0] += e2 * w0; acc[2][1] += e2 * w1;
                    acc[3][0] += e3 * w0; acc[3][1] += e3 * w1;
                }
            }
            #pragma unroll
            for (int r = 0; r < 4; ++r)
                #pragma unroll
                for (int c = 0; c < 2; ++c)
                    tbuf[(m0 + r) * 48 + o0 + c] += acc[r][c] + f2b[o0 + c];
        }
        __syncthreads();
    }

    // store: t_out pixel-major; block's 1920 floats are contiguous & identical layout
    {
        float* dst = t_out + ((size_t)(b * 4096 + hw0)) * 480;
        for (int q = tid; q < 480; q += THREADS)
            *(float4*)(dst + q * 4) = *(const float4*)(tbuf + q * 4);
    }
}

// ---------------- Kernel B: depthwise 3x3 conv (SAME) + transpose to pixel-major ----------------
__global__ __launch_bounds__(THREADS) void kb_conv(
    const float* __restrict__ x, const float* __restrict__ t_in,
    const float* __restrict__ dw_w, const float* __restrict__ dw_b,
    float* __restrict__ z0)
{
    __shared__ float ct[100 * 97];     // 10x10 halo tile x 96 ch, stride 97 (bank pad)
    const int tid = threadIdx.x;
    const int blk = blockIdx.x;
    const int n = blk >> 6;            // image (b*10+c)
    const int tile = blk & 63;
    const int th0 = (tile >> 3) << 3;
    const int tw0 = (tile & 7) << 3;
    const int b = n / 10, c = n % 10;

    // x half of cat: channels 0..47, planar layout
    for (int idx = tid; idx < 4800; idx += THREADS) {
        int f = idx / 100, p = idx % 100;
        int py = p / 10, px = p % 10;
        int gh = th0 + py - 1, gw = tw0 + px - 1;
        float v = 0.f;
        if ((unsigned)gh < 64u && (unsigned)gw < 64u)
            v = x[((size_t)n * 48 + f) * 4096 + gh * 64 + gw];
        ct[p * 97 + f] = v;
    }
    // y half of cat: channels 48..95, from t (pixel-major)
    for (int idx = tid; idx < 4800; idx += THREADS) {
        int p = idx / 48, f = idx % 48;
        int py = p / 10, px = p % 10;
        int gh = th0 + py - 1, gw = tw0 + px - 1;
        float v = 0.f;
        if ((unsigned)gh < 64u && (unsigned)gw < 64u)
            v = t_in[(size_t)(b * 4096 + gh * 64 + gw) * 480 + c * 48 + f];
        ct[p * 97 + 48 + f] = v;
    }
    __syncthreads();

    #pragma unroll 4
    for (int it = 0; it < 24; ++it) {
        int oidx = tid + it * THREADS;   // 24*256 == 6144 == 64px * 96ch
        int pxl = oidx / 96, ch = oidx % 96;
        int py = pxl >> 3, pxx = pxl & 7;
        const float* wp = dw_w + ch * 9;
        float acc = dw_b[ch];
        #pragma unroll
        for (int dy = 0; dy < 3; ++dy)
            #pragma unroll
            for (int dx = 0; dx < 3; ++dx)
                acc += ct[((py + dy) * 10 + pxx + dx) * 97 + ch] * wp[dy * 3 + dx];
        z0[((size_t)n * 4096 + (th0 + py) * 64 + (tw0 + pxx)) * 96 + ch] = acc;
    }
}

// ---------------- Kernel C: LN + pw1+gelu+pw2 + shortcut, cooperative 64px/block ----------------
// LDS: zb 25.6KB + hb 25.6KB = 51.2KB -> 3 blocks/CU
__global__ __launch_bounds__(THREADS, 3) void kc_mlp(
    const float* __restrict__ x, const float* __restrict__ t_in,
    const float* __restrict__ z0,
    const float* __restrict__ ln_g, const float* __restrict__ ln_b,
    const float* __restrict__ pw1_w, const float* __restrict__ pw1_b,
    const float* __restrict__ pw2_w, const float* __restrict__ pw2_b,
    const float* __restrict__ sc_w, const float* __restrict__ sc_b,
    float* __restrict__ out)
{
    __shared__ float zb[64 * 100];   // z rows (stride 100, 16B aligned); later: cat rows
    __shared__ float hb[64 * 100];   // h chunk rows (stride 100); later: out staging [f*66+px]
    const int tid = threadIdx.x;
    const int blk = blockIdx.x;       // 5120
    const int n   = blk >> 6;         // image 0..79
    const int hw0 = (blk & 63) << 6;  // 64-pixel run
    const size_t pixbase = (size_t)n * 4096 + hw0;

    // ---- stage z0 (contiguous 6144 floats) ----
    for (int idx = tid; idx < 1536; idx += THREADS) {
        float4 v = *(const float4*)(z0 + pixbase * 96 + (size_t)idx * 4);
        int p = idx / 24, c0 = (idx % 24) * 4;
        *(float4*)(&zb[p * 100 + c0]) = v;
    }
    __syncthreads();

    // ---- LayerNorm in place: one lane per pixel ----
    if (tid < 64) {
        float* r = zb + tid * 100;
        float mu = 0.f;
        #pragma unroll
        for (int k = 0; k < 96; ++k) mu += r[k];
        mu *= (1.f / 96.f);
        float var = 0.f;
        #pragma unroll
        for (int k = 0; k < 96; ++k) { float d = r[k] - mu; var += d * d; }
        var *= (1.f / 96.f);
        float rs = rsqrtf(var + 1e-6f);
        #pragma unroll
        for (int k = 0; k < 96; ++k) r[k] = (r[k] - mu) * rs * ln_g[k] + ln_b[k];
    }
    __syncthreads();

    const int pxg = tid >> 4;          // 0..15 (4 pixels each)
    const int sub = tid & 15;          // jg in phase2, fg in phase3
    const int f0  = sub * 3;           // phase3 cols

    float facc[4][3];
    #pragma unroll
    for (int r = 0; r < 4; ++r)
        #pragma unroll
        for (int c = 0; c < 3; ++c) facc[r][c] = pw2_b[f0 + c];

    for (int jc = 0; jc < 4; ++jc) {
        // ---- phase2: h chunk = gelu(z @ pw1[:, jc*96 : jc*96+96] + b), 4px x 6j per thread ----
        {
            const int j0 = jc * 96 + sub * 6;
            const float* zr = zb + pxg * 400;
            float h[4][6] = {};
            for (int k = 0; k < 96; k += 4) {
                float4 a0 = *(const float4*)(zr + k);
                float4 a1 = *(const float4*)(zr + 100 + k);
                float4 a2 = *(const float4*)(zr + 200 + k);
                float4 a3 = *(const float4*)(zr + 300 + k);
                #pragma unroll
                for (int kk = 0; kk < 4; ++kk) {
                    const float* wr = pw1_w + (k + kk) * 384 + j0;
                    const float e0 = (&a0.x)[kk], e1 = (&a1.x)[kk], e2 = (&a2.x)[kk], e3 = (&a3.x)[kk];
                    #pragma unroll
                    for (int c = 0; c < 6; ++c) {
                        const float w = wr[c];
                        h[0][c] += e0 * w; h[1][c] += e1 * w;
                        h[2][c] += e2 * w; h[3][c] += e3 * w;
                    }
                }
            }
            #pragma unroll
            for (int r = 0; r < 4; ++r)
                #pragma unroll
                for (int c = 0; c < 6; ++c) {
                    float v = h[r][c] + pw1_b[j0 + c];
                    v = 0.5f * v * (1.f + erff(v * 0.70710678118654752f));
                    hb[(pxg * 4 + r) * 100 + sub * 6 + c] = v;
                }
        }
        __syncthreads();

        // ---- phase3: facc += h_chunk @ pw2[jc*96 : ..., :], 4px x 3f per thread ----
        {
            const float* hr = hb + pxg * 400;
            for (int k = 0; k < 96; k += 4) {
                float4 a0 = *(const float4*)(hr + k);
                float4 a1 = *(const float4*)(hr + 100 + k);
                float4 a2 = *(const float4*)(hr + 200 + k);
                float4 a3 = *(const float4*)(hr + 300 + k);
                #pragma unroll
                for (int kk = 0; kk < 4; ++kk) {
                    const float* wr = pw2_w + (jc * 96 + k + kk) * 48 + f0;
                    const float w0 = wr[0], w1 = wr[1], w2 = wr[2];
                    const float e0 = (&a0.x)[kk], e1 = (&a1.x)[kk], e2 = (&a2.x)[kk], e3 = (&a3.x)[kk];
                    facc[0][0] += e0 * w0; facc[0][1] += e0 * w1; facc[0][2] += e0 * w2;
                    facc[1][0] += e1 * w0; facc[1][1] += e1 * w1; facc[1][2] += e1 * w2;
                    facc[2][0] += e2 * w0; facc[2][1] += e2 * w1; facc[2][2] += e2 * w2;
                    facc[3][0] += e3 * w0; facc[3][1] += e3 * w1; facc[3][2] += e3 * w2;
                }
            }
        }
        __syncthreads();   // hb reused by next chunk; zb re-read
    }

    // ---- stage cat (x planar ch 0..47, t pixel-major ch 48..95) into zb ----
    for (int idx = tid; idx < 768; idx += THREADS) {
        int ch = idx >> 4, p0 = (idx & 15) << 2;
        float4 v = *(const float4*)(x + ((size_t)n * 48 + ch) * 4096 + hw0 + p0);
        zb[(p0 + 0) * 100 + ch] = v.x; zb[(p0 + 1) * 100 + ch] = v.y;
        zb[(p0 + 2) * 100 + ch] = v.z; zb[(p0 + 3) * 100 + ch] = v.w;
    }
    {
        const size_t tb = ((size_t)(n / 10) * 4096 + hw0);
        const int coff = (n % 10) * 48;
        for (int idx = tid; idx < 768; idx += THREADS) {
            int p = idx / 12, u0 = (idx % 12) * 4;
            float4 v = *(const float4*)(t_in + (tb + p) * 480 + coff + u0);
            *(float4*)(&zb[p * 100 + 48 + u0]) = v;
        }
    }
    __syncthreads();

    // ---- shortcut: facc += cat @ sc_w^T (sc_w is [48 out][96 in]) ----
    {
        const float* cr = zb + pxg * 400;
        for (int k = 0; k < 96; k += 4) {
            float4 a0 = *(const float4*)(cr + k);
            float4 a1 = *(const float4*)(cr + 100 + k);
            float4 a2 = *(const float4*)(cr + 200 + k);
            float4 a3 = *(const float4*)(cr + 300 + k);
            float4 w0 = *(const float4*)(sc_w + (f0 + 0) * 96 + k);
            float4 w1 = *(const float4*)(sc_w + (f0 + 1) * 96 + k);
            float4 w2 = *(const float4*)(sc_w + (f0 + 2) * 96 + k);
            #pragma unroll
            for (int kk = 0; kk < 4; ++kk) {
                const float e0 = (&a0.x)[kk], e1 = (&a1.x)[kk], e2 = (&a2.x)[kk], e3 = (&a3.x)[kk];
                const float q0 = (&w0.x)[kk], q1 = (&w1.x)[kk], q2 = (&w2.x)[kk];
                facc[0][0] += e0 * q0; facc[0][1] += e0 * q1; facc[0][2] += e0 * q2;
                facc[1][0] += e1 * q0; facc[1][1] += e1 * q1; facc[1][2] += e1 * q2;
                facc[2][0] += e2 * q0; facc[2][1] += e2 * q1; facc[2][2] += e2 * q2;
                facc[3][0] += e3 * q0; facc[3][1] += e3 * q1; facc[3][2] += e3 * q2;
            }
        }
    }
    __syncthreads();   // zb/hb done; reuse hb for output staging

    // ---- epilogue: stage [f][px] (stride 66), then coalesced float4 stores ----
    #pragma unroll
    for (int r = 0; r < 4; ++r)
        #pragma unroll
        for (int c = 0; c < 3; ++c)
            hb[(f0 + c) * 66 + pxg * 4 + r] = facc[r][c] + sc_b[f0 + c];
    __syncthreads();
    for (int idx = tid; idx < 768; idx += THREADS) {
        int f = idx / 16, p0 = (idx % 16) * 4;
        float4 v;
        v.x = hb[f * 66 + p0]; v.y = hb[f * 66 + p0 + 1];
        v.z = hb[f * 66 + p0 + 2]; v.w = hb[f * 66 + p0 + 3];
        *(float4*)(out + ((size_t)n * 48 + f) * 4096 + hw0 + p0) = v;
    }
}

extern "C" void kernel_launch(void* const* d_in, const int* in_sizes, int n_in,
                              void* d_out, int out_size, void* d_ws, size_t ws_size,
                              hipStream_t stream) {
    const float* x      = (const float*)d_in[0];
    const float* qkv_w  = (const float*)d_in[1];
    const float* qkv_b  = (const float*)d_in[2];
    const float* proj_w = (const float*)d_in[3];
    const float* proj_b = (const float*)d_in[4];
    const float* ff1_w  = (const float*)d_in[5];
    const float* ff1_b  = (const float*)d_in[6];
    const float* ff2_w  = (const float*)d_in[7];
    const float* ff2_b  = (const float*)d_in[8];
    const float* dw_w   = (const float*)d_in[9];
    const float* dw_b   = (const float*)d_in[10];
    const float* ln_g   = (const float*)d_in[11];
    const float* ln_b   = (const float*)d_in[12];
    const float* pw1_w  = (const float*)d_in[13];
    const float* pw1_b  = (const float*)d_in[14];
    const float* pw2_w  = (const float*)d_in[15];
    const float* pw2_b  = (const float*)d_in[16];
    const float* sc_w   = (const float*)d_in[17];
    const float* sc_b   = (const float*)d_in[18];
    float* out = (float*)d_out;

    // workspace: t_final (B*H*W,10,48) = 15,728,640 f ; z0 (80*4096,96) = 31,457,280 f
    float* t_out = (float*)d_ws;
    float* z0    = t_out + 15728640ull;

    ka_transformer<<<8192, THREADS, 0, stream>>>(x, qkv_w, qkv_b, proj_w, proj_b,
                                                 ff1_w, ff1_b, ff2_w, ff2_b, t_out);
    kb_conv<<<5120, THREADS, 0, stream>>>(x, t_out, dw_w, dw_b, z0);
    kc_mlp<<<5120, THREADS, 0, stream>>>(x, t_out, z0, ln_g, ln_b,
                                         pw1_w, pw1_b, pw2_w, pw2_b, sc_w, sc_b, out);
}